// Round 5
// baseline (1409.165 us; speedup 1.0000x reference)
//
#include <hip/hip_runtime.h>

#define TT 2048
#define BB 256
#define II 64
#define HH 128
#define CHP 16          // x/gx chunk depth in timesteps
#define GXS 532         // gx row stride in floats (slot = col*4 + gate, padded)

typedef __fp16 f16;
typedef __fp16 h2  __attribute__((ext_vector_type(2)));
typedef __fp16 v8h __attribute__((ext_vector_type(8)));
typedef float  v4f __attribute__((ext_vector_type(4)));

union HI { int i; h2 h; };
__device__ __forceinline__ h2  i2h(int v) { HI u; u.i = v; return u.h; }
__device__ __forceinline__ int h2i(h2 v)  { HI u; u.h = v; return u.i; }

__device__ __forceinline__ float fsig(float x) {
  return __builtin_amdgcn_rcpf(1.0f + __expf(-x));
}
__device__ __forceinline__ float ftanh(float x) {
  return 1.0f - 2.0f * __builtin_amdgcn_rcpf(1.0f + __expf(2.0f * x));
}

// Raw barrier: LDS-drain only; global loads/stores stay in flight.
__device__ __forceinline__ void bar_lgkm() {
  asm volatile("s_waitcnt lgkmcnt(0)\n\ts_barrier" ::: "memory");
}

// One block per batch row, 512 threads = 8 waves = 2 waves/SIMD (the R2
// envelope, known-good on this harness; the 768-thread helper variant killed
// the container twice and is abandoned).
// Changes vs R2:
//  (1) 12 independent depth-1 MFMA accumulators (grouped by af operand so the
//      first 3 start on lgkmcnt(3)); gate sums = 3 scalar adds in epilogue.
//      Removes one exposed MFMA-result-latency level from the chain.
//  (2) CLS==0: per-step global h store replaced by an LDS ring write
//      (hring[16][128]); all 512 threads flush 8 rows coalesced every 8th
//      step. Ring write at step s -> row s&15; flush at step s (s%8==0)
//      reads rows s-8..s-1: disjoint, barrier-separated, race-free.
template <int CLS>
__global__ __launch_bounds__(512, 1) void gru_mfma(
    const float* __restrict__ x,
    const float* __restrict__ Wir, const float* __restrict__ Wiz, const float* __restrict__ Win,
    const float* __restrict__ bir, const float* __restrict__ biz, const float* __restrict__ bin_,
    const float* __restrict__ Whr, const float* __restrict__ Whz, const float* __restrict__ Whn,
    const float* __restrict__ bhn, const float* __restrict__ Wc,  const float* __restrict__ bc,
    float* __restrict__ hh, float* __restrict__ out)
{
  const int t = threadIdx.x, b = blockIdx.x;
  const int w = t >> 6;     // wave id 0..7
  const int l = t & 63;     // lane
  const int q = l >> 4;     // quad
  const int r = l & 15;
  const int nc = 16 * w + r;   // this lane's output column

  __shared__ __attribute__((aligned(16))) f16   hbuf[2][HH];       // h state, dbuf
  __shared__ __attribute__((aligned(16))) f16   xch[2][CHP][72];   // x chunks (f16, A-layout)
  __shared__ __attribute__((aligned(16))) float gxb[2][CHP][GXS];  // gx = x@Wi + bi (f32), dbuf
  __shared__ __attribute__((aligned(16))) float hring[16][HH];     // h history ring (CLS==0)
  __shared__ float cpart[2][128];                                   // CLS==1 classifier partials

  // ---- resident B fragments: B[k=32kt+8q+j][n=nc] ----
  // kt 0..3 of br_/bz_ = Whr/Whz; kt 4..5 = Wir/Wiz (reused by gx precompute).
  v8h br_[6], bz_[6], bnh_[4], bnx_[2];
  for (int kt = 0; kt < 6; ++kt) {
    v8h vr, vz;
    for (int j = 0; j < 8; ++j) {
      const int kg = 32 * kt + 8 * q + j;
      vr[j] = (f16)((kg < HH) ? Whr[kg * HH + nc] : Wir[(kg - HH) * HH + nc]);
      vz[j] = (f16)((kg < HH) ? Whz[kg * HH + nc] : Wiz[(kg - HH) * HH + nc]);
    }
    br_[kt] = vr; bz_[kt] = vz;
  }
  for (int kt = 0; kt < 4; ++kt) {
    v8h v;
    for (int j = 0; j < 8; ++j) v[j] = (f16)Whn[(32 * kt + 8 * q + j) * HH + nc];
    bnh_[kt] = v;
  }
  for (int kt = 0; kt < 2; ++kt) {
    v8h v;
    for (int j = 0; j < 8; ++j) v[j] = (f16)Win[(32 * kt + 8 * q + j) * HH + nc];
    bnx_[kt] = v;
  }

  const float birc = bir[nc], bizc = biz[nc], binc = bin_[nc], bhnc = bhn[nc];
  float wc = 0.f, bc0 = 0.f;
  if (CLS == 1) { wc = Wc[nc]; bc0 = bc[0]; }

  // gx precompute: 16 timesteps packed into M; A[ts=r][k=8q+j (+32 for ax1)];
  // C[ts=4q+j][col=nc]. Bias folded in as accumulator init.
  auto precomp = [&](int pn, v8h ax0, v8h ax1) {
    v4f cr = {birc, birc, birc, birc};
    v4f cz = {bizc, bizc, bizc, bizc};
    v4f cn = {binc, binc, binc, binc};
    cr = __builtin_amdgcn_mfma_f32_16x16x32_f16(ax0, br_[4],  cr, 0, 0, 0);
    cz = __builtin_amdgcn_mfma_f32_16x16x32_f16(ax0, bz_[4],  cz, 0, 0, 0);
    cn = __builtin_amdgcn_mfma_f32_16x16x32_f16(ax0, bnx_[0], cn, 0, 0, 0);
    cr = __builtin_amdgcn_mfma_f32_16x16x32_f16(ax1, br_[5],  cr, 0, 0, 0);
    cz = __builtin_amdgcn_mfma_f32_16x16x32_f16(ax1, bz_[5],  cz, 0, 0, 0);
    cn = __builtin_amdgcn_mfma_f32_16x16x32_f16(ax1, bnx_[1], cn, 0, 0, 0);
    #pragma unroll
    for (int j = 0; j < 4; ++j) {
      v4f pk; pk[0] = cr[j]; pk[1] = cz[j]; pk[2] = cn[j]; pk[3] = 0.f;
      *(v4f*)&gxb[pn][4 * q + j][nc * 4] = pk;
    }
  };

  // ---- prologue: x chunks 0,1 -> LDS; gx chunk 0 ----
  const int xrow = t >> 5, xcol = (t & 31) * 2;   // thread covers 2 f32 of one row
  float2 xr;
  {
    float2 xA = *(const float2*)(x + ((size_t)(0   + xrow) * BB + b) * II + xcol);
    float2 xB = *(const float2*)(x + ((size_t)(CHP + xrow) * BB + b) * II + xcol);
    if (t < HH) { hbuf[0][t] = (f16)0.f; hbuf[1][t] = (f16)0.f; }
    *(int*)&xch[0][xrow][xcol] = h2i(__builtin_amdgcn_cvt_pkrtz(xA.x, xA.y));
    __syncthreads();
    {
      v8h a0x = *(const v8h*)&xch[0][r][8 * q];
      v8h a1x = *(const v8h*)&xch[0][r][32 + 8 * q];
      precomp(0, a0x, a1x);
    }
    *(int*)&xch[1][xrow][xcol] = h2i(__builtin_amdgcn_cvt_pkrtz(xB.x, xB.y));
    __syncthreads();
  }

  // gx prefetch register (step 0)
  v4f gp = *(const v4f*)&gxb[0][0][nc * 4];

  v8h af[4] = {};            // non-(r==0) lanes stay zero forever
  float hst = 0.f;

  #pragma unroll 1
  for (int s = 0; s < TT; ++s) {
    const int cur = s & 1, nxt = cur ^ 1;
    const int sc = s & (CHP - 1), p = (s >> 4) & 1;
    const bool pc = (sc == 0) && (s + CHP < TT);

    // CLS==0: every 8th step, flush ring rows s-8..s-1 to global (all 512
    // threads, coalesced 512B/row). Rows are barrier-separated from their
    // writers; current step writes row s&15 (disjoint).
    if (CLS == 0 && (s & 7) == 0 && s >= 8) {
      const int row = s - 8 + w;                      // wave w flushes one row
      const float2 hv = *(const float2*)&hring[row & 15][2 * l];
      *(float2*)(hh + ((size_t)row * BB + b) * HH + 2 * l) = hv;  // fire-and-forget
    }

    // chunk boundary: A-frag reads for next chunk's gx precompute; global
    // loads for the chunk after that (15 steps of latency slack).
    v8h ax0 = {}, ax1 = {};
    if (pc) {
      ax0 = *(const v8h*)&xch[p ^ 1][r][8 * q];
      ax1 = *(const v8h*)&xch[p ^ 1][r][32 + 8 * q];
    }
    if (sc == 0 && s + 2 * CHP < TT) {
      xr = *(const float2*)(x + ((size_t)(s + 2 * CHP + xrow) * BB + b) * II + xcol);
    }

    // CLS==1: pick up previous step's classifier partials
    float cred = 0.f;
    if (CLS == 1 && w == 7 && s > 0) cred = cpart[nxt][l] + cpart[nxt][64 + l];

    // h A-frags (barrier-dependent; 4 reads, r==0 lanes)
    if (r == 0) {
      af[0] = *(const v8h*)&hbuf[cur][8 * q];
      af[1] = *(const v8h*)&hbuf[cur][32 + 8 * q];
      af[2] = *(const v8h*)&hbuf[cur][64 + 8 * q];
      af[3] = *(const v8h*)&hbuf[cur][96 + 8 * q];
    }

    // MFMA phase: 12 INDEPENDENT depth-1 accumulators, grouped by af operand
    // so the first group starts after the first ds_read returns (lgkmcnt(3)).
    // Gate totals are formed by scalar adds in the epilogue (elem 0 only).
    const v4f vz0 = {0.f, 0.f, 0.f, 0.f};
    v4f ra, na, za, rb, nb, zb, rc, n_c, zc, rd, nd, zd;
    ra  = __builtin_amdgcn_mfma_f32_16x16x32_f16(af[0], br_[0],  vz0, 0, 0, 0);
    na  = __builtin_amdgcn_mfma_f32_16x16x32_f16(af[0], bnh_[0], vz0, 0, 0, 0);
    za  = __builtin_amdgcn_mfma_f32_16x16x32_f16(af[0], bz_[0],  vz0, 0, 0, 0);
    rb  = __builtin_amdgcn_mfma_f32_16x16x32_f16(af[1], br_[1],  vz0, 0, 0, 0);
    nb  = __builtin_amdgcn_mfma_f32_16x16x32_f16(af[1], bnh_[1], vz0, 0, 0, 0);
    zb  = __builtin_amdgcn_mfma_f32_16x16x32_f16(af[1], bz_[1],  vz0, 0, 0, 0);
    rc  = __builtin_amdgcn_mfma_f32_16x16x32_f16(af[2], br_[2],  vz0, 0, 0, 0);
    n_c = __builtin_amdgcn_mfma_f32_16x16x32_f16(af[2], bnh_[2], vz0, 0, 0, 0);
    zc  = __builtin_amdgcn_mfma_f32_16x16x32_f16(af[2], bz_[2],  vz0, 0, 0, 0);
    rd  = __builtin_amdgcn_mfma_f32_16x16x32_f16(af[3], br_[3],  vz0, 0, 0, 0);
    nd  = __builtin_amdgcn_mfma_f32_16x16x32_f16(af[3], bnh_[3], vz0, 0, 0, 0);
    zd  = __builtin_amdgcn_mfma_f32_16x16x32_f16(af[3], bz_[3],  vz0, 0, 0, 0);

    // gx for THIS step (prefetched last step); prefetch next step's now
    // (barrier-independent, hides under the MFMA tail).
    const v4f g = gp;
    {
      const int sn = s + 1;
      if (sn < TT) {
        const int pn2 = (sn >> 4) & 1, scn = sn & (CHP - 1);
        gp = *(const v4f*)&gxb[pn2][scn][nc * 4];
      }
    }

    // epilogue: C row 0 = elem 0 of quad-0 lanes; col = nc
    if (q == 0) {
      const float arS = ((ra[0] + rb[0]) + (rc[0] + rd[0])) + g[0];
      const float anS = ((na[0] + nb[0]) + (n_c[0] + nd[0])) + bhnc;
      const float rr  = fsig(arS);
      const float nn  = ftanh(g[2] + rr * anS);
      const float azS = ((za[0] + zb[0]) + (zc[0] + zd[0])) + g[1];
      const float zz  = fsig(azS);
      hst = nn + zz * (hst - nn);
      hbuf[nxt][nc] = (f16)hst;
      if (CLS == 0) hring[s & 15][nc] = hst;   // LDS ring, flushed every 8 steps
      if (CLS == 1) cpart[cur][nc] = hst * wc;
    }

    // CLS==1: finish previous step's classifier (overlaps other waves' work)
    if (CLS == 1 && w == 7 && s > 0) {
      cred += __shfl_xor(cred, 1, 64);
      cred += __shfl_xor(cred, 2, 64);
      cred += __shfl_xor(cred, 4, 64);
      cred += __shfl_xor(cred, 8, 64);
      cred += __shfl_xor(cred, 16, 64);
      cred += __shfl_xor(cred, 32, 64);
      if (l == 0) out[(size_t)(s - 1) * BB + b] = fsig(cred + bc0);
    }

    // amortized x-projection for chunk c+1 (6 MFMAs/wave per 16 steps)
    if (pc) precomp(p ^ 1, ax0, ax1);

    // stage chunk c+2's x (loaded at this chunk's sc==0) into xch[p]
    if (sc == CHP - 1 && s + CHP + 1 < TT) {
      *(int*)&xch[p][xrow][xcol] = h2i(__builtin_amdgcn_cvt_pkrtz(xr.x, xr.y));
    }

    bar_lgkm();
  }

  // tails
  if (CLS == 0) {           // flush ring rows TT-8..TT-1
    const int row = TT - 8 + w;
    const float2 hv = *(const float2*)&hring[row & 15][2 * l];
    *(float2*)(hh + ((size_t)row * BB + b) * HH + 2 * l) = hv;
  }
  if (CLS == 1 && w == 7) {
    float cred = cpart[1][l] + cpart[1][64 + l];
    cred += __shfl_xor(cred, 1, 64);
    cred += __shfl_xor(cred, 2, 64);
    cred += __shfl_xor(cred, 4, 64);
    cred += __shfl_xor(cred, 8, 64);
    cred += __shfl_xor(cred, 16, 64);
    cred += __shfl_xor(cred, 32, 64);
    if (l == 0) out[(size_t)(TT - 1) * BB + b] = fsig(cred + bc0);
  }
}

// out[row] = sigmoid(dot(hh[row][:], Wc) + bc); row = t*BB + b.
// 4 threads per row (32 cols each), 64 rows/block, coalesced f32 reads.
__global__ __launch_bounds__(256) void gru_cls(
    const float* __restrict__ hh, const float* __restrict__ Wc,
    const float* __restrict__ bc, float* __restrict__ out)
{
  const int t  = threadIdx.x;
  const int g4 = t & 3;
  const size_t row = (size_t)blockIdx.x * 64 + (t >> 2);
  const float* hp = hh + row * HH + 32 * g4;
  const float* wp = Wc + 32 * g4;
  float acc = 0.f;
  #pragma unroll
  for (int i = 0; i < 8; ++i) {
    v4f h4 = *(const v4f*)(hp + 4 * i);
    v4f w4 = *(const v4f*)(wp + 4 * i);
    acc += h4[0] * w4[0] + h4[1] * w4[1] + h4[2] * w4[2] + h4[3] * w4[3];
  }
  acc += __shfl_xor(acc, 1, 64);
  acc += __shfl_xor(acc, 2, 64);
  if (g4 == 0) out[row] = fsig(acc + bc[0]);
}

extern "C" void kernel_launch(void* const* d_in, const int* in_sizes, int n_in,
                              void* d_out, int out_size, void* d_ws, size_t ws_size,
                              hipStream_t stream) {
  const float* x    = (const float*)d_in[0];
  const float* Wir  = (const float*)d_in[1];
  const float* Wiz  = (const float*)d_in[2];
  const float* Win  = (const float*)d_in[3];
  const float* bir  = (const float*)d_in[4];
  const float* biz  = (const float*)d_in[5];
  const float* bin_ = (const float*)d_in[6];
  const float* Whr  = (const float*)d_in[7];
  const float* Whz  = (const float*)d_in[8];
  const float* Whn  = (const float*)d_in[9];
  const float* bhn  = (const float*)d_in[10];
  const float* Wc   = (const float*)d_in[11];
  const float* bc   = (const float*)d_in[12];
  float* out = (float*)d_out;

  const size_t need = (size_t)TT * BB * HH * sizeof(float);  // 256 MiB h history
  if (d_ws != nullptr && ws_size >= need) {
    float* hh = (float*)d_ws;
    gru_mfma<0><<<dim3(BB), dim3(512), 0, stream>>>(
        x, Wir, Wiz, Win, bir, biz, bin_, Whr, Whz, Whn, bhn, Wc, bc, hh, out);
    gru_cls<<<dim3((TT * BB) / 64), dim3(256), 0, stream>>>(hh, Wc, bc, out);
  } else {
    gru_mfma<1><<<dim3(BB), dim3(512), 0, stream>>>(
        x, Wir, Wiz, Win, bir, biz, bin_, Whr, Whz, Whn, bhn, Wc, bc, nullptr, out);
  }
}

// Round 6
// 951.647 us; speedup vs baseline: 1.4808x; 1.4808x over previous
//
#include <hip/hip_runtime.h>

#define TT 2048
#define BB 256
#define II 64
#define HH 128
#define CHP 16          // x/gx chunk depth in timesteps
#define NCH (TT / CHP)  // 128 chunks
#define GXS 532         // gx row stride in floats (slot = col*4 + gate, padded)

typedef __fp16 f16;
typedef __fp16 h2  __attribute__((ext_vector_type(2)));
typedef __fp16 v8h __attribute__((ext_vector_type(8)));
typedef float  v4f __attribute__((ext_vector_type(4)));

union HI { int i; h2 h; };
__device__ __forceinline__ h2  i2h(int v) { HI u; u.i = v; return u.h; }
__device__ __forceinline__ int h2i(h2 v)  { HI u; u.h = v; return u.i; }

__device__ __forceinline__ float fsig(float x) {
  return __builtin_amdgcn_rcpf(1.0f + __expf(-x));
}
__device__ __forceinline__ float ftanh(float x) {
  return 1.0f - 2.0f * __builtin_amdgcn_rcpf(1.0f + __expf(2.0f * x));
}

// Raw barrier: LDS-drain only; global loads/stores stay in flight.
__device__ __forceinline__ void bar_lgkm() {
  asm volatile("s_waitcnt lgkmcnt(0)\n\ts_barrier" ::: "memory");
}

// One block per batch row, 512 threads = 8 waves = 2 waves/SIMD (the R2
// envelope -- best verified config, 1167 us). This version is R2's step
// semantics EXACTLY (depth-2 MFMA chains, direct global h store, same
// buffer protocol), restructured as: outer chunk loop x fully-unrolled
// 16-step inner loop. All sc predicates, cur/nxt toggles and gxb/xch LDS
// offsets become compile-time immediates; hh store uses a rolling pointer.
// Rationale: R2 counters show the step is instruction-issue-bound
// (MFMA 414 + VALU ~530 of 1366 cyc); unrolling deletes the per-step
// rolling-state arithmetic that #pragma unroll 1 forced.
template <int CLS>
__global__ __launch_bounds__(512, 1) void gru_mfma(
    const float* __restrict__ x,
    const float* __restrict__ Wir, const float* __restrict__ Wiz, const float* __restrict__ Win,
    const float* __restrict__ bir, const float* __restrict__ biz, const float* __restrict__ bin_,
    const float* __restrict__ Whr, const float* __restrict__ Whz, const float* __restrict__ Whn,
    const float* __restrict__ bhn, const float* __restrict__ Wc,  const float* __restrict__ bc,
    float* __restrict__ hh, float* __restrict__ out)
{
  const int t = threadIdx.x, b = blockIdx.x;
  const int w = t >> 6;     // wave id 0..7
  const int l = t & 63;     // lane
  const int q = l >> 4;     // quad
  const int r = l & 15;
  const int nc = 16 * w + r;   // this lane's output column

  __shared__ __attribute__((aligned(16))) f16   hbuf[2][HH];       // h state, dbuf
  __shared__ __attribute__((aligned(16))) f16   xch[2][CHP][72];   // x chunks (f16, A-layout)
  __shared__ __attribute__((aligned(16))) float gxb[2][CHP][GXS];  // gx = x@Wi + bi (f32), dbuf
  __shared__ float cpart[2][128];                                   // CLS==1 classifier partials

  // ---- resident B fragments: B[k=32kt+8q+j][n=nc] ----
  // kt 0..3 of br_/bz_ = Whr/Whz; kt 4..5 = Wir/Wiz (reused by gx precompute).
  v8h br_[6], bz_[6], bnh_[4], bnx_[2];
  for (int kt = 0; kt < 6; ++kt) {
    v8h vr, vz;
    for (int j = 0; j < 8; ++j) {
      const int kg = 32 * kt + 8 * q + j;
      vr[j] = (f16)((kg < HH) ? Whr[kg * HH + nc] : Wir[(kg - HH) * HH + nc]);
      vz[j] = (f16)((kg < HH) ? Whz[kg * HH + nc] : Wiz[(kg - HH) * HH + nc]);
    }
    br_[kt] = vr; bz_[kt] = vz;
  }
  for (int kt = 0; kt < 4; ++kt) {
    v8h v;
    for (int j = 0; j < 8; ++j) v[j] = (f16)Whn[(32 * kt + 8 * q + j) * HH + nc];
    bnh_[kt] = v;
  }
  for (int kt = 0; kt < 2; ++kt) {
    v8h v;
    for (int j = 0; j < 8; ++j) v[j] = (f16)Win[(32 * kt + 8 * q + j) * HH + nc];
    bnx_[kt] = v;
  }

  const float birc = bir[nc], bizc = biz[nc], binc = bin_[nc], bhnc = bhn[nc];
  float wc = 0.f, bc0 = 0.f;
  if (CLS == 1) { wc = Wc[nc]; bc0 = bc[0]; }

  // gx precompute: 16 timesteps packed into M; A[ts=r][k=8q+j (+32 for ax1)];
  // C[ts=4q+j][col=nc]. Bias folded in as accumulator init.
  auto precomp = [&](int pn, v8h ax0, v8h ax1) {
    v4f cr = {birc, birc, birc, birc};
    v4f cz = {bizc, bizc, bizc, bizc};
    v4f cn = {binc, binc, binc, binc};
    cr = __builtin_amdgcn_mfma_f32_16x16x32_f16(ax0, br_[4],  cr, 0, 0, 0);
    cz = __builtin_amdgcn_mfma_f32_16x16x32_f16(ax0, bz_[4],  cz, 0, 0, 0);
    cn = __builtin_amdgcn_mfma_f32_16x16x32_f16(ax0, bnx_[0], cn, 0, 0, 0);
    cr = __builtin_amdgcn_mfma_f32_16x16x32_f16(ax1, br_[5],  cr, 0, 0, 0);
    cz = __builtin_amdgcn_mfma_f32_16x16x32_f16(ax1, bz_[5],  cz, 0, 0, 0);
    cn = __builtin_amdgcn_mfma_f32_16x16x32_f16(ax1, bnx_[1], cn, 0, 0, 0);
    #pragma unroll
    for (int j = 0; j < 4; ++j) {
      v4f pk; pk[0] = cr[j]; pk[1] = cz[j]; pk[2] = cn[j]; pk[3] = 0.f;
      *(v4f*)&gxb[pn][4 * q + j][nc * 4] = pk;
    }
  };

  // ---- prologue: x chunks 0,1 -> LDS; gx chunk 0 ----
  const int xrow = t >> 5, xcol = (t & 31) * 2;   // thread covers 2 f32 of one row
  float2 xr;
  {
    float2 xA = *(const float2*)(x + ((size_t)(0   + xrow) * BB + b) * II + xcol);
    float2 xB = *(const float2*)(x + ((size_t)(CHP + xrow) * BB + b) * II + xcol);
    if (t < HH) { hbuf[0][t] = (f16)0.f; hbuf[1][t] = (f16)0.f; }
    *(int*)&xch[0][xrow][xcol] = h2i(__builtin_amdgcn_cvt_pkrtz(xA.x, xA.y));
    __syncthreads();
    {
      v8h a0x = *(const v8h*)&xch[0][r][8 * q];
      v8h a1x = *(const v8h*)&xch[0][r][32 + 8 * q];
      precomp(0, a0x, a1x);
    }
    *(int*)&xch[1][xrow][xcol] = h2i(__builtin_amdgcn_cvt_pkrtz(xB.x, xB.y));
    __syncthreads();
  }

  // gx prefetch register (step 0)
  v4f gp = *(const v4f*)&gxb[0][0][nc * 4];

  v8h af[4] = {};            // non-(r==0) lanes stay zero forever
  float hst = 0.f;
  float* hps = (CLS == 0) ? (hh + (size_t)b * HH + nc) : nullptr;  // rolling h ptr

  for (int c = 0; c < NCH; ++c) {
    const int p = c & 1;
    const bool pc = (c + 1 < NCH);   // precompute gx for next chunk?
    const bool ld = (c + 2 < NCH);   // load x for chunk after next?

    // chunk-boundary reads (post-barrier, latency hidden under steps 0..14):
    v8h ax0 = {}, ax1 = {};
    if (pc) {
      ax0 = *(const v8h*)&xch[p ^ 1][r][8 * q];
      ax1 = *(const v8h*)&xch[p ^ 1][r][32 + 8 * q];
    }
    if (ld) {
      xr = *(const float2*)(x + ((size_t)((c + 2) * CHP + xrow) * BB + b) * II + xcol);
    }

    #pragma unroll
    for (int sc = 0; sc < CHP; ++sc) {
      const int s = c * CHP + sc;          // affine; sc is a literal
      const int cur = sc & 1, nxt = cur ^ 1;

      // h A-frags first (latency starts at barrier release; 4 reads, r==0)
      if (r == 0) {
        af[0] = *(const v8h*)&hbuf[cur][8 * q];
        af[1] = *(const v8h*)&hbuf[cur][32 + 8 * q];
        af[2] = *(const v8h*)&hbuf[cur][64 + 8 * q];
        af[3] = *(const v8h*)&hbuf[cur][96 + 8 * q];
      }

      // CLS==1: pick up previous step's classifier partials
      float cred = 0.f;
      if (CLS == 1 && w == 7 && (sc > 0 || c > 0))
        cred = cpart[nxt][l] + cpart[nxt][64 + l];

      // MFMA phase: K=128 (h only), 12 MFMAs, depth-2 chains, order r->n->z
      // so the epilogue transcendentals overlap z issue. (R2-exact.)
      const v4f vz0 = {0.f, 0.f, 0.f, 0.f};
      v4f ar0, ar1, an0, an1, az0, az1;
      ar0 = __builtin_amdgcn_mfma_f32_16x16x32_f16(af[0], br_[0], vz0, 0, 0, 0);
      ar1 = __builtin_amdgcn_mfma_f32_16x16x32_f16(af[2], br_[2], vz0, 0, 0, 0);
      ar0 = __builtin_amdgcn_mfma_f32_16x16x32_f16(af[1], br_[1], ar0, 0, 0, 0);
      ar1 = __builtin_amdgcn_mfma_f32_16x16x32_f16(af[3], br_[3], ar1, 0, 0, 0);
      an0 = __builtin_amdgcn_mfma_f32_16x16x32_f16(af[0], bnh_[0], vz0, 0, 0, 0);
      an1 = __builtin_amdgcn_mfma_f32_16x16x32_f16(af[2], bnh_[2], vz0, 0, 0, 0);
      an0 = __builtin_amdgcn_mfma_f32_16x16x32_f16(af[1], bnh_[1], an0, 0, 0, 0);
      an1 = __builtin_amdgcn_mfma_f32_16x16x32_f16(af[3], bnh_[3], an1, 0, 0, 0);
      az0 = __builtin_amdgcn_mfma_f32_16x16x32_f16(af[0], bz_[0], vz0, 0, 0, 0);
      az1 = __builtin_amdgcn_mfma_f32_16x16x32_f16(af[2], bz_[2], vz0, 0, 0, 0);
      az0 = __builtin_amdgcn_mfma_f32_16x16x32_f16(af[1], bz_[1], az0, 0, 0, 0);
      az1 = __builtin_amdgcn_mfma_f32_16x16x32_f16(af[3], bz_[3], az1, 0, 0, 0);

      // gx for THIS step (prefetched last step); prefetch next step's now.
      // Offsets are compile-time: pn2/scn are literals per unrolled position.
      const v4f g = gp;
      if (sc < CHP - 1) {
        gp = *(const v4f*)&gxb[p][sc + 1][nc * 4];
      } else if (c + 1 < NCH) {
        gp = *(const v4f*)&gxb[p ^ 1][0][nc * 4];
      }

      // epilogue: C row 0 = elem 0 of quad-0 lanes; col = nc
      if (q == 0) {
        const float arS = ar0[0] + ar1[0] + g[0];
        const float anS = an0[0] + an1[0] + bhnc;
        const float rr  = fsig(arS);
        const float nn  = ftanh(g[2] + rr * anS);
        const float azS = az0[0] + az1[0] + g[1];
        const float zz  = fsig(azS);
        hst = nn + zz * (hst - nn);
        hbuf[nxt][nc] = (f16)hst;
        if (CLS == 0) *hps = hst;            // fire-and-forget global store
        if (CLS == 1) cpart[cur][nc] = hst * wc;
      }
      if (CLS == 0) hps += BB * HH;          // rolling pointer (all lanes)

      // CLS==1: finish previous step's classifier (overlaps other waves)
      if (CLS == 1 && w == 7 && (sc > 0 || c > 0)) {
        cred += __shfl_xor(cred, 1, 64);
        cred += __shfl_xor(cred, 2, 64);
        cred += __shfl_xor(cred, 4, 64);
        cred += __shfl_xor(cred, 8, 64);
        cred += __shfl_xor(cred, 16, 64);
        cred += __shfl_xor(cred, 32, 64);
        if (l == 0) out[(size_t)(s - 1) * BB + b] = fsig(cred + bc0);
      }

      // amortized x-projection for chunk c+1 (6 MFMAs/wave per 16 steps)
      if (sc == 0 && pc) precomp(p ^ 1, ax0, ax1);

      // stage chunk c+2's x (loaded at top of this chunk) into xch[p]
      if (sc == CHP - 1 && ld) {
        *(int*)&xch[p][xrow][xcol] = h2i(__builtin_amdgcn_cvt_pkrtz(xr.x, xr.y));
      }

      bar_lgkm();
    }
  }

  if (CLS == 1 && w == 7) {
    float cred = cpart[1][l] + cpart[1][64 + l];
    cred += __shfl_xor(cred, 1, 64);
    cred += __shfl_xor(cred, 2, 64);
    cred += __shfl_xor(cred, 4, 64);
    cred += __shfl_xor(cred, 8, 64);
    cred += __shfl_xor(cred, 16, 64);
    cred += __shfl_xor(cred, 32, 64);
    if (l == 0) out[(size_t)(TT - 1) * BB + b] = fsig(cred + bc0);
  }
}

// out[row] = sigmoid(dot(hh[row][:], Wc) + bc); row = t*BB + b.
// 4 threads per row (32 cols each), 64 rows/block, coalesced f32 reads.
__global__ __launch_bounds__(256) void gru_cls(
    const float* __restrict__ hh, const float* __restrict__ Wc,
    const float* __restrict__ bc, float* __restrict__ out)
{
  const int t  = threadIdx.x;
  const int g4 = t & 3;
  const size_t row = (size_t)blockIdx.x * 64 + (t >> 2);
  const float* hp = hh + row * HH + 32 * g4;
  const float* wp = Wc + 32 * g4;
  float acc = 0.f;
  #pragma unroll
  for (int i = 0; i < 8; ++i) {
    v4f h4 = *(const v4f*)(hp + 4 * i);
    v4f w4 = *(const v4f*)(wp + 4 * i);
    acc += h4[0] * w4[0] + h4[1] * w4[1] + h4[2] * w4[2] + h4[3] * w4[3];
  }
  acc += __shfl_xor(acc, 1, 64);
  acc += __shfl_xor(acc, 2, 64);
  if (g4 == 0) out[row] = fsig(acc + bc[0]);
}

extern "C" void kernel_launch(void* const* d_in, const int* in_sizes, int n_in,
                              void* d_out, int out_size, void* d_ws, size_t ws_size,
                              hipStream_t stream) {
  const float* x    = (const float*)d_in[0];
  const float* Wir  = (const float*)d_in[1];
  const float* Wiz  = (const float*)d_in[2];
  const float* Win  = (const float*)d_in[3];
  const float* bir  = (const float*)d_in[4];
  const float* biz  = (const float*)d_in[5];
  const float* bin_ = (const float*)d_in[6];
  const float* Whr  = (const float*)d_in[7];
  const float* Whz  = (const float*)d_in[8];
  const float* Whn  = (const float*)d_in[9];
  const float* bhn  = (const float*)d_in[10];
  const float* Wc   = (const float*)d_in[11];
  const float* bc   = (const float*)d_in[12];
  float* out = (float*)d_out;

  const size_t need = (size_t)TT * BB * HH * sizeof(float);  // 256 MiB h history
  if (d_ws != nullptr && ws_size >= need) {
    float* hh = (float*)d_ws;
    gru_mfma<0><<<dim3(BB), dim3(512), 0, stream>>>(
        x, Wir, Wiz, Win, bir, biz, bin_, Whr, Whz, Whn, bhn, Wc, bc, hh, out);
    gru_cls<<<dim3((TT * BB) / 64), dim3(256), 0, stream>>>(hh, Wc, bc, out);
  } else {
    gru_mfma<1><<<dim3(BB), dim3(512), 0, stream>>>(
        x, Wir, Wiz, Win, bir, biz, bin_, Whr, Whz, Whn, bhn, Wc, bc, nullptr, out);
  }
}

// Round 7
// 866.626 us; speedup vs baseline: 1.6260x; 1.0981x over previous
//
#include <hip/hip_runtime.h>

#define TT 2048
#define BB 256
#define II 64
#define HH 128
#define CHP 16          // x/gx chunk depth in timesteps
#define NCH (TT / CHP)  // 128 chunks
#define GXS 532         // gx row stride in floats (slot = col*4 + gate, padded)

#define LOG2E  1.4426950408889634f
#define LOG2E2 2.8853900817779268f

typedef __fp16 f16;
typedef __fp16 h2  __attribute__((ext_vector_type(2)));
typedef __fp16 v8h __attribute__((ext_vector_type(8)));
typedef float  v4f __attribute__((ext_vector_type(4)));

union HI { int i; h2 h; };
__device__ __forceinline__ h2  i2h(int v) { HI u; u.i = v; return u.h; }
__device__ __forceinline__ int h2i(h2 v)  { HI u; u.h = v; return u.i; }

// v_exp_f32 computes 2^x natively.
__device__ __forceinline__ float fexp2(float x) {
  float r; asm("v_exp_f32 %0, %1" : "=v"(r) : "v"(x)); return r;
}
__device__ __forceinline__ float fsig(float x) {       // cls kernel only
  return __builtin_amdgcn_rcpf(1.0f + __expf(-x));
}

// Raw barrier: LDS-drain only; global loads/stores stay in flight.
__device__ __forceinline__ void bar_lgkm() {
  asm volatile("s_waitcnt lgkmcnt(0)\n\ts_barrier" ::: "memory");
}

// One block per batch row, 512 threads = 8 waves = 2 waves/SIMD. R6 structure
// (outer chunk loop x fully-unrolled 16-step inner loop) with chain surgery:
//  (1) MFMA order operand-sequential af0->af1->af2->af3 (r/n interleaved,
//      z last): first MFMA starts on the FIRST ds_read return; reads (12cyc)
//      outrun MFMA issue (19cyc) so no later stalls; r/n still finish early
//      enough to overlap the epilogue transcendentals with z issue.
//  (2) gx precompute spread 1-op-per-step over sc=0..9, placed in the af-read
//      wait bubble (ax0/ax1 read at chunk top return before af[0]).
//  (3) exp2 prescale: log2e folded into r/z weights+biases, 2*log2e into n;
//      sigmoid/tanh = rcp(1+exp2(+-x)) -- removes 3 serial v_mul from the
//      epilogue tail. Numerically == __expf (same mul, done at load time).
//  (4) h history stored as f16 via uniform SGPR base + per-lane offset
//      (halves write traffic; SALU pointer roll).
template <int CLS>
__global__ __launch_bounds__(512, 1) void gru_mfma(
    const float* __restrict__ x,
    const float* __restrict__ Wir, const float* __restrict__ Wiz, const float* __restrict__ Win,
    const float* __restrict__ bir, const float* __restrict__ biz, const float* __restrict__ bin_,
    const float* __restrict__ Whr, const float* __restrict__ Whz, const float* __restrict__ Whn,
    const float* __restrict__ bhn, const float* __restrict__ Wc,  const float* __restrict__ bc,
    f16* __restrict__ hh, float* __restrict__ out)
{
  const int t = threadIdx.x, b = blockIdx.x;
  const int w = t >> 6;     // wave id 0..7
  const int l = t & 63;     // lane
  const int q = l >> 4;     // quad
  const int r = l & 15;
  const int nc = 16 * w + r;   // this lane's output column

  __shared__ __attribute__((aligned(16))) f16   hbuf[2][HH];       // h state, dbuf
  __shared__ __attribute__((aligned(16))) f16   xch[2][CHP][72];   // x chunks (f16, A-layout)
  __shared__ __attribute__((aligned(16))) float gxb[2][CHP][GXS];  // gx (prescaled), dbuf
  __shared__ float cpart[2][128];                                   // CLS==1 classifier partials

  // ---- resident B fragments: B[k=32kt+8q+j][n=nc], prescaled ----
  // kt 0..3 of br_/bz_ = Whr/Whz; kt 4..5 = Wir/Wiz (reused by gx precompute).
  v8h br_[6], bz_[6], bnh_[4], bnx_[2];
  for (int kt = 0; kt < 6; ++kt) {
    v8h vr, vz;
    for (int j = 0; j < 8; ++j) {
      const int kg = 32 * kt + 8 * q + j;
      vr[j] = (f16)(LOG2E * ((kg < HH) ? Whr[kg * HH + nc] : Wir[(kg - HH) * HH + nc]));
      vz[j] = (f16)(LOG2E * ((kg < HH) ? Whz[kg * HH + nc] : Wiz[(kg - HH) * HH + nc]));
    }
    br_[kt] = vr; bz_[kt] = vz;
  }
  for (int kt = 0; kt < 4; ++kt) {
    v8h v;
    for (int j = 0; j < 8; ++j) v[j] = (f16)(LOG2E2 * Whn[(32 * kt + 8 * q + j) * HH + nc]);
    bnh_[kt] = v;
  }
  for (int kt = 0; kt < 2; ++kt) {
    v8h v;
    for (int j = 0; j < 8; ++j) v[j] = (f16)(LOG2E2 * Win[(32 * kt + 8 * q + j) * HH + nc]);
    bnx_[kt] = v;
  }

  const float birc = LOG2E * bir[nc],  bizc = LOG2E * biz[nc];
  const float binc = LOG2E2 * bin_[nc], bhnc = LOG2E2 * bhn[nc];
  float wc = 0.f, bc0 = 0.f;
  if (CLS == 1) { wc = Wc[nc]; bc0 = bc[0]; }

  // full gx precompute (prologue only): 16 timesteps packed into M;
  // A[ts=r][k=8q+j (+32 for ax1)]; C[ts=4q+j][col=nc]. Bias = acc init.
  auto precomp_full = [&](int pn, v8h ax0, v8h ax1) {
    v4f cr = {birc, birc, birc, birc};
    v4f cz = {bizc, bizc, bizc, bizc};
    v4f cn = {binc, binc, binc, binc};
    cr = __builtin_amdgcn_mfma_f32_16x16x32_f16(ax0, br_[4],  cr, 0, 0, 0);
    cz = __builtin_amdgcn_mfma_f32_16x16x32_f16(ax0, bz_[4],  cz, 0, 0, 0);
    cn = __builtin_amdgcn_mfma_f32_16x16x32_f16(ax0, bnx_[0], cn, 0, 0, 0);
    cr = __builtin_amdgcn_mfma_f32_16x16x32_f16(ax1, br_[5],  cr, 0, 0, 0);
    cz = __builtin_amdgcn_mfma_f32_16x16x32_f16(ax1, bz_[5],  cz, 0, 0, 0);
    cn = __builtin_amdgcn_mfma_f32_16x16x32_f16(ax1, bnx_[1], cn, 0, 0, 0);
    #pragma unroll
    for (int j = 0; j < 4; ++j) {
      v4f pk; pk[0] = cr[j]; pk[1] = cz[j]; pk[2] = cn[j]; pk[3] = 0.f;
      *(v4f*)&gxb[pn][4 * q + j][nc * 4] = pk;
    }
  };

  // ---- prologue: x chunks 0,1 -> LDS; gx chunk 0 ----
  const int xrow = t >> 5, xcol = (t & 31) * 2;   // thread covers 2 f32 of one row
  float2 xr;
  {
    float2 xA = *(const float2*)(x + ((size_t)(0   + xrow) * BB + b) * II + xcol);
    float2 xB = *(const float2*)(x + ((size_t)(CHP + xrow) * BB + b) * II + xcol);
    if (t < HH) { hbuf[0][t] = (f16)0.f; hbuf[1][t] = (f16)0.f; }
    *(int*)&xch[0][xrow][xcol] = h2i(__builtin_amdgcn_cvt_pkrtz(xA.x, xA.y));
    __syncthreads();
    {
      v8h a0x = *(const v8h*)&xch[0][r][8 * q];
      v8h a1x = *(const v8h*)&xch[0][r][32 + 8 * q];
      precomp_full(0, a0x, a1x);
    }
    *(int*)&xch[1][xrow][xcol] = h2i(__builtin_amdgcn_cvt_pkrtz(xB.x, xB.y));
    __syncthreads();
  }

  // gx prefetch register (step 0)
  v4f gp = *(const v4f*)&gxb[0][0][nc * 4];

  v8h af[4] = {};            // non-(r==0) lanes stay zero forever
  float hst = 0.f;
  f16* hup = (CLS == 0) ? (hh + (size_t)b * HH) : nullptr;  // UNIFORM rolling base
  v4f cpr, cpz, cpn;                                        // spread-precomp accs

  for (int c = 0; c < NCH; ++c) {
    const int p = c & 1;
    const bool pc = (c + 1 < NCH);   // precompute gx for next chunk?
    const bool ld = (c + 2 < NCH);   // load x for chunk after next?

    // chunk-top reads: ax frags for the spread precompute (returns BEFORE the
    // first step's af reads -> the sc==0 precomp MFMA fills the af bubble),
    // and global x loads for chunk c+2 (15 steps of latency slack).
    v8h ax0 = {}, ax1 = {};
    if (pc) {
      ax0 = *(const v8h*)&xch[p ^ 1][r][8 * q];
      ax1 = *(const v8h*)&xch[p ^ 1][r][32 + 8 * q];
    }
    if (ld) {
      xr = *(const float2*)(x + ((size_t)((c + 2) * CHP + xrow) * BB + b) * II + xcol);
    }

    #pragma unroll
    for (int sc = 0; sc < CHP; ++sc) {
      const int s = c * CHP + sc;          // affine; sc is a literal
      const int cur = sc & 1, nxt = cur ^ 1;

      // h A-frags first (latency starts at barrier release; 4 reads, r==0)
      if (r == 0) {
        af[0] = *(const v8h*)&hbuf[cur][8 * q];
        af[1] = *(const v8h*)&hbuf[cur][32 + 8 * q];
        af[2] = *(const v8h*)&hbuf[cur][64 + 8 * q];
        af[3] = *(const v8h*)&hbuf[cur][96 + 8 * q];
      }

      // spread gx precompute: one op per step in the af-wait bubble.
      if (pc) {
        if (sc == 0) {
          v4f ir = {birc, birc, birc, birc};
          cpr = __builtin_amdgcn_mfma_f32_16x16x32_f16(ax0, br_[4], ir, 0, 0, 0);
        } else if (sc == 1) {
          v4f iz = {bizc, bizc, bizc, bizc};
          cpz = __builtin_amdgcn_mfma_f32_16x16x32_f16(ax0, bz_[4], iz, 0, 0, 0);
        } else if (sc == 2) {
          v4f in_ = {binc, binc, binc, binc};
          cpn = __builtin_amdgcn_mfma_f32_16x16x32_f16(ax0, bnx_[0], in_, 0, 0, 0);
        } else if (sc == 3) {
          cpr = __builtin_amdgcn_mfma_f32_16x16x32_f16(ax1, br_[5], cpr, 0, 0, 0);
        } else if (sc == 4) {
          cpz = __builtin_amdgcn_mfma_f32_16x16x32_f16(ax1, bz_[5], cpz, 0, 0, 0);
        } else if (sc == 5) {
          cpn = __builtin_amdgcn_mfma_f32_16x16x32_f16(ax1, bnx_[1], cpn, 0, 0, 0);
        } else if (sc >= 6 && sc < 10) {
          const int j = sc - 6;
          v4f pk; pk[0] = cpr[j]; pk[1] = cpz[j]; pk[2] = cpn[j]; pk[3] = 0.f;
          *(v4f*)&gxb[p ^ 1][4 * q + j][nc * 4] = pk;
        }
      }

      // CLS==1: pick up previous step's classifier partials
      float cred = 0.f;
      if (CLS == 1 && w == 7 && (sc > 0 || c > 0))
        cred = cpart[nxt][l] + cpart[nxt][64 + l];

      // MFMA phase: operand-sequential, r/n interleaved, z last.
      // Dep distance >=2 on every accumulator chain.
      const v4f vz0 = {0.f, 0.f, 0.f, 0.f};
      v4f ar0, ar1, an0, an1, az0, az1;
      ar0 = __builtin_amdgcn_mfma_f32_16x16x32_f16(af[0], br_[0],  vz0, 0, 0, 0);
      an0 = __builtin_amdgcn_mfma_f32_16x16x32_f16(af[0], bnh_[0], vz0, 0, 0, 0);
      ar0 = __builtin_amdgcn_mfma_f32_16x16x32_f16(af[1], br_[1],  ar0, 0, 0, 0);
      an0 = __builtin_amdgcn_mfma_f32_16x16x32_f16(af[1], bnh_[1], an0, 0, 0, 0);
      ar1 = __builtin_amdgcn_mfma_f32_16x16x32_f16(af[2], br_[2],  vz0, 0, 0, 0);
      an1 = __builtin_amdgcn_mfma_f32_16x16x32_f16(af[2], bnh_[2], vz0, 0, 0, 0);
      ar1 = __builtin_amdgcn_mfma_f32_16x16x32_f16(af[3], br_[3],  ar1, 0, 0, 0);
      an1 = __builtin_amdgcn_mfma_f32_16x16x32_f16(af[3], bnh_[3], an1, 0, 0, 0);
      az0 = __builtin_amdgcn_mfma_f32_16x16x32_f16(af[0], bz_[0],  vz0, 0, 0, 0);
      az1 = __builtin_amdgcn_mfma_f32_16x16x32_f16(af[2], bz_[2],  vz0, 0, 0, 0);
      az0 = __builtin_amdgcn_mfma_f32_16x16x32_f16(af[1], bz_[1],  az0, 0, 0, 0);
      az1 = __builtin_amdgcn_mfma_f32_16x16x32_f16(af[3], bz_[3],  az1, 0, 0, 0);

      // gx for THIS step (prefetched last step); prefetch next step's now.
      const v4f g = gp;
      if (sc < CHP - 1) {
        gp = *(const v4f*)&gxb[p][sc + 1][nc * 4];
      } else if (c + 1 < NCH) {
        gp = *(const v4f*)&gxb[p ^ 1][0][nc * 4];
      }

      // epilogue: C row 0 = elem 0 of quad-0 lanes; col = nc.
      // All preacts are prescaled by log2e (r,z) / 2*log2e (n) -> exp2 direct.
      if (q == 0) {
        const float arS = ar0[0] + ar1[0] + g[0];
        const float rr  = __builtin_amdgcn_rcpf(1.f + fexp2(-arS));
        const float anS = an0[0] + an1[0] + bhnc;
        const float nn  = 1.f - 2.f * __builtin_amdgcn_rcpf(1.f + fexp2(g[2] + rr * anS));
        const float azS = az0[0] + az1[0] + g[1];
        const float zz  = __builtin_amdgcn_rcpf(1.f + fexp2(-azS));
        hst = nn + zz * (hst - nn);
        const f16 hf = (f16)hst;
        hbuf[nxt][nc] = hf;
        if (CLS == 0) hup[nc] = hf;          // saddr-form fire-and-forget store
        if (CLS == 1) cpart[cur][nc] = hst * wc;
      }
      if (CLS == 0) hup += BB * HH;          // uniform -> SALU roll

      // CLS==1: finish previous step's classifier (overlaps other waves)
      if (CLS == 1 && w == 7 && (sc > 0 || c > 0)) {
        cred += __shfl_xor(cred, 1, 64);
        cred += __shfl_xor(cred, 2, 64);
        cred += __shfl_xor(cred, 4, 64);
        cred += __shfl_xor(cred, 8, 64);
        cred += __shfl_xor(cred, 16, 64);
        cred += __shfl_xor(cred, 32, 64);
        if (l == 0) out[(size_t)(s - 1) * BB + b] = fsig(cred + bc0);
      }

      // stage chunk c+2's x (loaded at top of this chunk) into xch[p]
      if (sc == CHP - 1 && ld) {
        *(int*)&xch[p][xrow][xcol] = h2i(__builtin_amdgcn_cvt_pkrtz(xr.x, xr.y));
      }

      bar_lgkm();
    }
  }

  if (CLS == 1 && w == 7) {
    float cred = cpart[1][l] + cpart[1][64 + l];
    cred += __shfl_xor(cred, 1, 64);
    cred += __shfl_xor(cred, 2, 64);
    cred += __shfl_xor(cred, 4, 64);
    cred += __shfl_xor(cred, 8, 64);
    cred += __shfl_xor(cred, 16, 64);
    cred += __shfl_xor(cred, 32, 64);
    if (l == 0) out[(size_t)(TT - 1) * BB + b] = fsig(cred + bc0);
  }
}

// out[row] = sigmoid(dot(hh[row][:], Wc) + bc); row = t*BB + b. hh is f16.
// 4 threads per row (32 cols each), 64 rows/block, coalesced 16B reads.
__global__ __launch_bounds__(256) void gru_cls(
    const f16* __restrict__ hh, const float* __restrict__ Wc,
    const float* __restrict__ bc, float* __restrict__ out)
{
  const int t  = threadIdx.x;
  const int g4 = t & 3;
  const size_t row = (size_t)blockIdx.x * 64 + (t >> 2);
  const f16* hp = hh + row * HH + 32 * g4;
  const float* wp = Wc + 32 * g4;
  float acc = 0.f;
  #pragma unroll
  for (int i = 0; i < 4; ++i) {
    v8h h8 = *(const v8h*)(hp + 8 * i);
    const float* wq = wp + 8 * i;
    #pragma unroll
    for (int j = 0; j < 8; ++j) acc += (float)h8[j] * wq[j];
  }
  acc += __shfl_xor(acc, 1, 64);
  acc += __shfl_xor(acc, 2, 64);
  if (g4 == 0) out[row] = fsig(acc + bc[0]);
}

extern "C" void kernel_launch(void* const* d_in, const int* in_sizes, int n_in,
                              void* d_out, int out_size, void* d_ws, size_t ws_size,
                              hipStream_t stream) {
  const float* x    = (const float*)d_in[0];
  const float* Wir  = (const float*)d_in[1];
  const float* Wiz  = (const float*)d_in[2];
  const float* Win  = (const float*)d_in[3];
  const float* bir  = (const float*)d_in[4];
  const float* biz  = (const float*)d_in[5];
  const float* bin_ = (const float*)d_in[6];
  const float* Whr  = (const float*)d_in[7];
  const float* Whz  = (const float*)d_in[8];
  const float* Whn  = (const float*)d_in[9];
  const float* bhn  = (const float*)d_in[10];
  const float* Wc   = (const float*)d_in[11];
  const float* bc   = (const float*)d_in[12];
  float* out = (float*)d_out;

  const size_t need = (size_t)TT * BB * HH * sizeof(f16);  // 128 MiB h history
  if (d_ws != nullptr && ws_size >= need) {
    f16* hh = (f16*)d_ws;
    gru_mfma<0><<<dim3(BB), dim3(512), 0, stream>>>(
        x, Wir, Wiz, Win, bir, biz, bin_, Whr, Whz, Whn, bhn, Wc, bc, hh, out);
    gru_cls<<<dim3((TT * BB) / 64), dim3(256), 0, stream>>>(hh, Wc, bc, out);
  } else {
    gru_mfma<1><<<dim3(BB), dim3(512), 0, stream>>>(
        x, Wir, Wiz, Win, bir, biz, bin_, Whr, Whz, Whn, bhn, Wc, bc, nullptr, out);
  }
}

// Round 8
// 769.701 us; speedup vs baseline: 1.8308x; 1.1259x over previous
//
#include <hip/hip_runtime.h>

#define TT 2048
#define BB 256
#define II 64
#define HH 128
#define CHP 16          // x/gx chunk depth in timesteps
#define NCH (TT / CHP)  // 128 chunks
#define GXS 532         // gx row stride in floats (slot = col*4 + gate, padded)

#define LOG2E  1.4426950408889634f
#define LOG2E2 2.8853900817779268f

typedef __fp16 f16;
typedef __fp16 h2  __attribute__((ext_vector_type(2)));
typedef __fp16 v8h __attribute__((ext_vector_type(8)));
typedef float  v4f __attribute__((ext_vector_type(4)));
typedef int    v4i __attribute__((ext_vector_type(4)));

union HI { int i; h2 h; };
__device__ __forceinline__ h2  i2h(int v) { HI u; u.i = v; return u.h; }
__device__ __forceinline__ int h2i(h2 v)  { HI u; u.h = v; return u.i; }

// v_exp_f32 computes 2^x natively.
__device__ __forceinline__ float fexp2(float x) {
  float r; asm("v_exp_f32 %0, %1" : "=v"(r) : "v"(x)); return r;
}
__device__ __forceinline__ float fsig(float x) {       // cls kernel only
  return __builtin_amdgcn_rcpf(1.0f + __expf(-x));
}

// Raw barrier: LDS-drain only; global loads/stores stay in flight.
__device__ __forceinline__ void bar_lgkm() {
  asm volatile("s_waitcnt lgkmcnt(0)\n\ts_barrier" ::: "memory");
}

// One block per batch row, 512 threads = 8 waves = 2 waves/SIMD. R7 structure
// with the h-projection moved to i8 MFMA (mfma_i32_16x16x64_i8, 2x f16 rate):
//   - K=128 per gate = 2 i8 MFMAs (vs 4 f16): pipe 24 -> 12 slices/SIMD.
//   - h state kept f32 in-register; quantized to i8 (x127) only as the
//     projection input; stored in hq8[2][128] (byte/col). A/B use the SAME
//     self-consistent k-slot mapping (frag f, quad q, byte j <-> k=64f+16q+j)
//     so any HW byte-permutation cancels in the dot product; C layout is
//     shape-determined (row0 = elem0 of q==0 lanes), dtype-independent.
//   - W quantized per-column (scale 127/max|W_col|) in the prologue; dequant
//     constants fold log2e (r,z) / 2*log2e (n) for the exp2 epilogue.
//   - gx (x-projection) stays f16 MFMA + f32 LDS exactly as before.
template <int CLS>
__global__ __launch_bounds__(512, 1) void gru_mfma(
    const float* __restrict__ x,
    const float* __restrict__ Wir, const float* __restrict__ Wiz, const float* __restrict__ Win,
    const float* __restrict__ bir, const float* __restrict__ biz, const float* __restrict__ bin_,
    const float* __restrict__ Whr, const float* __restrict__ Whz, const float* __restrict__ Whn,
    const float* __restrict__ bhn, const float* __restrict__ Wc,  const float* __restrict__ bc,
    f16* __restrict__ hh, float* __restrict__ out)
{
  const int t = threadIdx.x, b = blockIdx.x;
  const int w = t >> 6;     // wave id 0..7
  const int l = t & 63;     // lane
  const int q = l >> 4;     // quad
  const int r = l & 15;
  const int nc = 16 * w + r;   // this lane's output column

  __shared__ __attribute__((aligned(16))) signed char hq8[2][HH];  // i8 h, dbuf
  __shared__ __attribute__((aligned(16))) f16   xch[2][CHP][72];   // x chunks (f16, A-layout)
  __shared__ __attribute__((aligned(16))) float gxb[2][CHP][GXS];  // gx (prescaled), dbuf
  __shared__ float cpart[2][128];                                   // CLS==1 classifier partials

  // ---- i8 Wh fragments: frag f, byte j  <->  k = 64f + 16q + j ----
  v4i bqr[2], bqz[2], bqn[2];
  float invR, invZ, invN;
  {
    // pass 1: per-column max |W| (this lane sees 32 of 128 k per gate;
    // reduce across quads -- lanes r, r+16, r+32, r+48 share column nc)
    float mr = 1e-20f, mz = 1e-20f, mn = 1e-20f;
    for (int f = 0; f < 2; ++f)
      for (int j = 0; j < 16; ++j) {
        const int k = 64 * f + 16 * q + j;
        mr = fmaxf(mr, fabsf(Whr[k * HH + nc]));
        mz = fmaxf(mz, fabsf(Whz[k * HH + nc]));
        mn = fmaxf(mn, fabsf(Whn[k * HH + nc]));
      }
    mr = fmaxf(mr, __shfl_xor(mr, 16, 64)); mr = fmaxf(mr, __shfl_xor(mr, 32, 64));
    mz = fmaxf(mz, __shfl_xor(mz, 16, 64)); mz = fmaxf(mz, __shfl_xor(mz, 32, 64));
    mn = fmaxf(mn, __shfl_xor(mn, 16, 64)); mn = fmaxf(mn, __shfl_xor(mn, 32, 64));
    const float sr = 127.f / mr, sz = 127.f / mz, sn = 127.f / mn;
    invR = LOG2E  * mr / 16129.f;   // 127^2
    invZ = LOG2E  * mz / 16129.f;
    invN = LOG2E2 * mn / 16129.f;
    // pass 2: quantize + pack (prologue-only cost)
    for (int f = 0; f < 2; ++f) {
      union { signed char c[16]; v4i v; } ur, uz, un;
      for (int j = 0; j < 16; ++j) {
        const int k = 64 * f + 16 * q + j;
        ur.c[j] = (signed char)(int)rintf(Whr[k * HH + nc] * sr);
        uz.c[j] = (signed char)(int)rintf(Whz[k * HH + nc] * sz);
        un.c[j] = (signed char)(int)rintf(Whn[k * HH + nc] * sn);
      }
      bqr[f] = ur.v; bqz[f] = uz.v; bqn[f] = un.v;
    }
  }

  // ---- f16 Wi fragments for the gx precompute (log2e-prescaled) ----
  v8h wir[2], wiz[2], win2[2];
  for (int kt = 0; kt < 2; ++kt) {
    v8h vr, vz, vn;
    for (int j = 0; j < 8; ++j) {
      const int kg = 32 * kt + 8 * q + j;
      vr[j] = (f16)(LOG2E  * Wir[kg * HH + nc]);
      vz[j] = (f16)(LOG2E  * Wiz[kg * HH + nc]);
      vn[j] = (f16)(LOG2E2 * Win[kg * HH + nc]);
    }
    wir[kt] = vr; wiz[kt] = vz; win2[kt] = vn;
  }

  const float birc = LOG2E * bir[nc],  bizc = LOG2E * biz[nc];
  const float binc = LOG2E2 * bin_[nc], bhnc = LOG2E2 * bhn[nc];
  float wc = 0.f, bc0 = 0.f;
  if (CLS == 1) { wc = Wc[nc]; bc0 = bc[0]; }

  // full gx precompute (prologue only)
  auto precomp_full = [&](int pn, v8h ax0, v8h ax1) {
    v4f cr = {birc, birc, birc, birc};
    v4f cz = {bizc, bizc, bizc, bizc};
    v4f cn = {binc, binc, binc, binc};
    cr = __builtin_amdgcn_mfma_f32_16x16x32_f16(ax0, wir[0],  cr, 0, 0, 0);
    cz = __builtin_amdgcn_mfma_f32_16x16x32_f16(ax0, wiz[0],  cz, 0, 0, 0);
    cn = __builtin_amdgcn_mfma_f32_16x16x32_f16(ax0, win2[0], cn, 0, 0, 0);
    cr = __builtin_amdgcn_mfma_f32_16x16x32_f16(ax1, wir[1],  cr, 0, 0, 0);
    cz = __builtin_amdgcn_mfma_f32_16x16x32_f16(ax1, wiz[1],  cz, 0, 0, 0);
    cn = __builtin_amdgcn_mfma_f32_16x16x32_f16(ax1, win2[1], cn, 0, 0, 0);
    #pragma unroll
    for (int j = 0; j < 4; ++j) {
      v4f pk; pk[0] = cr[j]; pk[1] = cz[j]; pk[2] = cn[j]; pk[3] = 0.f;
      *(v4f*)&gxb[pn][4 * q + j][nc * 4] = pk;
    }
  };

  // ---- prologue: x chunks 0,1 -> LDS; gx chunk 0 ----
  const int xrow = t >> 5, xcol = (t & 31) * 2;   // thread covers 2 f32 of one row
  float2 xr;
  {
    float2 xA = *(const float2*)(x + ((size_t)(0   + xrow) * BB + b) * II + xcol);
    float2 xB = *(const float2*)(x + ((size_t)(CHP + xrow) * BB + b) * II + xcol);
    if (t < HH) { hq8[0][t] = 0; hq8[1][t] = 0; }
    *(int*)&xch[0][xrow][xcol] = h2i(__builtin_amdgcn_cvt_pkrtz(xA.x, xA.y));
    __syncthreads();
    {
      v8h a0x = *(const v8h*)&xch[0][r][8 * q];
      v8h a1x = *(const v8h*)&xch[0][r][32 + 8 * q];
      precomp_full(0, a0x, a1x);
    }
    *(int*)&xch[1][xrow][xcol] = h2i(__builtin_amdgcn_cvt_pkrtz(xB.x, xB.y));
    __syncthreads();
  }

  // gx prefetch register (step 0)
  v4f gp = *(const v4f*)&gxb[0][0][nc * 4];

  v4i ai0 = {0, 0, 0, 0}, ai1 = {0, 0, 0, 0};   // non-(r==0) lanes stay zero
  float hst = 0.f;
  f16* hup = (CLS == 0) ? (hh + (size_t)b * HH) : nullptr;  // UNIFORM rolling base
  v4f cpr, cpz, cpn;                                        // spread-precomp accs

  for (int c = 0; c < NCH; ++c) {
    const int p = c & 1;
    const bool pc = (c + 1 < NCH);   // precompute gx for next chunk?
    const bool ld = (c + 2 < NCH);   // load x for chunk after next?

    // chunk-top reads: ax frags for the spread precompute; global x loads for
    // chunk c+2 (15 steps of latency slack).
    v8h ax0 = {}, ax1 = {};
    if (pc) {
      ax0 = *(const v8h*)&xch[p ^ 1][r][8 * q];
      ax1 = *(const v8h*)&xch[p ^ 1][r][32 + 8 * q];
    }
    if (ld) {
      xr = *(const float2*)(x + ((size_t)((c + 2) * CHP + xrow) * BB + b) * II + xcol);
    }

    #pragma unroll
    for (int sc = 0; sc < CHP; ++sc) {
      const int s = c * CHP + sc;          // affine; sc is a literal
      const int cur = sc & 1, nxt = cur ^ 1;

      // i8 h A-frags (2 reads, r==0 lanes; 16B-aligned)
      if (r == 0) {
        ai0 = *(const v4i*)&hq8[cur][16 * q];
        ai1 = *(const v4i*)&hq8[cur][64 + 16 * q];
      }

      // spread gx precompute: one op per step in the af-wait bubble.
      if (pc) {
        if (sc == 0) {
          v4f ir = {birc, birc, birc, birc};
          cpr = __builtin_amdgcn_mfma_f32_16x16x32_f16(ax0, wir[0], ir, 0, 0, 0);
        } else if (sc == 1) {
          v4f iz = {bizc, bizc, bizc, bizc};
          cpz = __builtin_amdgcn_mfma_f32_16x16x32_f16(ax0, wiz[0], iz, 0, 0, 0);
        } else if (sc == 2) {
          v4f in_ = {binc, binc, binc, binc};
          cpn = __builtin_amdgcn_mfma_f32_16x16x32_f16(ax0, win2[0], in_, 0, 0, 0);
        } else if (sc == 3) {
          cpr = __builtin_amdgcn_mfma_f32_16x16x32_f16(ax1, wir[1], cpr, 0, 0, 0);
        } else if (sc == 4) {
          cpz = __builtin_amdgcn_mfma_f32_16x16x32_f16(ax1, wiz[1], cpz, 0, 0, 0);
        } else if (sc == 5) {
          cpn = __builtin_amdgcn_mfma_f32_16x16x32_f16(ax1, win2[1], cpn, 0, 0, 0);
        } else if (sc >= 6 && sc < 10) {
          const int j = sc - 6;
          v4f pk; pk[0] = cpr[j]; pk[1] = cpz[j]; pk[2] = cpn[j]; pk[3] = 0.f;
          *(v4f*)&gxb[p ^ 1][4 * q + j][nc * 4] = pk;
        }
      }

      // CLS==1: pick up previous step's classifier partials
      float cred = 0.f;
      if (CLS == 1 && w == 7 && (sc > 0 || c > 0))
        cred = cpart[nxt][l] + cpart[nxt][64 + l];

      // i8 MFMA phase: 2 K-halves x 3 gates, r first / n / z last.
      const v4i zi = {0, 0, 0, 0};
      v4i cr_, cn2, cz_;
      cr_ = __builtin_amdgcn_mfma_i32_16x16x64_i8(ai0, bqr[0], zi, 0, 0, 0);
      cn2 = __builtin_amdgcn_mfma_i32_16x16x64_i8(ai0, bqn[0], zi, 0, 0, 0);
      cz_ = __builtin_amdgcn_mfma_i32_16x16x64_i8(ai0, bqz[0], zi, 0, 0, 0);
      cr_ = __builtin_amdgcn_mfma_i32_16x16x64_i8(ai1, bqr[1], cr_, 0, 0, 0);
      cn2 = __builtin_amdgcn_mfma_i32_16x16x64_i8(ai1, bqn[1], cn2, 0, 0, 0);
      cz_ = __builtin_amdgcn_mfma_i32_16x16x64_i8(ai1, bqz[1], cz_, 0, 0, 0);

      // gx for THIS step (prefetched last step); prefetch next step's now.
      const v4f g = gp;
      if (sc < CHP - 1) {
        gp = *(const v4f*)&gxb[p][sc + 1][nc * 4];
      } else if (c + 1 < NCH) {
        gp = *(const v4f*)&gxb[p ^ 1][0][nc * 4];
      }

      // epilogue: C row 0 = elem 0 of quad-0 lanes; col = nc.
      // Dequant constants fold 1/127^2, per-column W scale, and log2e.
      if (q == 0) {
        const float arS = (float)cr_[0] * invR + g[0];
        const float rr  = __builtin_amdgcn_rcpf(1.f + fexp2(-arS));
        const float anS = (float)cn2[0] * invN + bhnc;
        const float nn  = 1.f - 2.f * __builtin_amdgcn_rcpf(1.f + fexp2(g[2] + rr * anS));
        const float azS = (float)cz_[0] * invZ + g[1];
        const float zz  = __builtin_amdgcn_rcpf(1.f + fexp2(-azS));
        hst = nn + zz * (hst - nn);
        hq8[nxt][nc] = (signed char)(int)rintf(hst * 127.f);   // i8 h for next step
        if (CLS == 0) hup[nc] = (f16)hst;    // saddr-form fire-and-forget store
        if (CLS == 1) cpart[cur][nc] = hst * wc;
      }
      if (CLS == 0) hup += BB * HH;          // uniform -> SALU roll

      // CLS==1: finish previous step's classifier (overlaps other waves)
      if (CLS == 1 && w == 7 && (sc > 0 || c > 0)) {
        cred += __shfl_xor(cred, 1, 64);
        cred += __shfl_xor(cred, 2, 64);
        cred += __shfl_xor(cred, 4, 64);
        cred += __shfl_xor(cred, 8, 64);
        cred += __shfl_xor(cred, 16, 64);
        cred += __shfl_xor(cred, 32, 64);
        if (l == 0) out[(size_t)(s - 1) * BB + b] = fsig(cred + bc0);
      }

      // stage chunk c+2's x (loaded at top of this chunk) into xch[p]
      if (sc == CHP - 1 && ld) {
        *(int*)&xch[p][xrow][xcol] = h2i(__builtin_amdgcn_cvt_pkrtz(xr.x, xr.y));
      }

      bar_lgkm();
    }
  }

  if (CLS == 1 && w == 7) {
    float cred = cpart[1][l] + cpart[1][64 + l];
    cred += __shfl_xor(cred, 1, 64);
    cred += __shfl_xor(cred, 2, 64);
    cred += __shfl_xor(cred, 4, 64);
    cred += __shfl_xor(cred, 8, 64);
    cred += __shfl_xor(cred, 16, 64);
    cred += __shfl_xor(cred, 32, 64);
    if (l == 0) out[(size_t)(TT - 1) * BB + b] = fsig(cred + bc0);
  }
}

// out[row] = sigmoid(dot(hh[row][:], Wc) + bc); row = t*BB + b. hh is f16.
// 4 threads per row (32 cols each), 64 rows/block, coalesced 16B reads.
__global__ __launch_bounds__(256) void gru_cls(
    const f16* __restrict__ hh, const float* __restrict__ Wc,
    const float* __restrict__ bc, float* __restrict__ out)
{
  const int t  = threadIdx.x;
  const int g4 = t & 3;
  const size_t row = (size_t)blockIdx.x * 64 + (t >> 2);
  const f16* hp = hh + row * HH + 32 * g4;
  const float* wp = Wc + 32 * g4;
  float acc = 0.f;
  #pragma unroll
  for (int i = 0; i < 4; ++i) {
    v8h h8 = *(const v8h*)(hp + 8 * i);
    const float* wq = wp + 8 * i;
    #pragma unroll
    for (int j = 0; j < 8; ++j) acc += (float)h8[j] * wq[j];
  }
  acc += __shfl_xor(acc, 1, 64);
  acc += __shfl_xor(acc, 2, 64);
  if (g4 == 0) out[row] = fsig(acc + bc[0]);
}

extern "C" void kernel_launch(void* const* d_in, const int* in_sizes, int n_in,
                              void* d_out, int out_size, void* d_ws, size_t ws_size,
                              hipStream_t stream) {
  const float* x    = (const float*)d_in[0];
  const float* Wir  = (const float*)d_in[1];
  const float* Wiz  = (const float*)d_in[2];
  const float* Win  = (const float*)d_in[3];
  const float* bir  = (const float*)d_in[4];
  const float* biz  = (const float*)d_in[5];
  const float* bin_ = (const float*)d_in[6];
  const float* Whr  = (const float*)d_in[7];
  const float* Whz  = (const float*)d_in[8];
  const float* Whn  = (const float*)d_in[9];
  const float* bhn  = (const float*)d_in[10];
  const float* Wc   = (const float*)d_in[11];
  const float* bc   = (const float*)d_in[12];
  float* out = (float*)d_out;

  const size_t need = (size_t)TT * BB * HH * sizeof(f16);  // 128 MiB h history
  if (d_ws != nullptr && ws_size >= need) {
    f16* hh = (f16*)d_ws;
    gru_mfma<0><<<dim3(BB), dim3(512), 0, stream>>>(
        x, Wir, Wiz, Win, bir, biz, bin_, Whr, Whz, Whn, bhn, Wc, bc, hh, out);
    gru_cls<<<dim3((TT * BB) / 64), dim3(256), 0, stream>>>(hh, Wc, bc, out);
  } else {
    gru_mfma<1><<<dim3(BB), dim3(512), 0, stream>>>(
        x, Wir, Wiz, Win, bir, biz, bin_, Whr, Whz, Whn, bhn, Wc, bc, nullptr, out);
  }
}